// Round 5
// baseline (128.929 us; speedup 1.0000x reference)
//
#include <hip/hip_runtime.h>
#include <hip/hip_bf16.h>

#define S_LEN 3072
#define E_DIM 1280
#define NH 16
#define HD 80      // head dim
#define HDP 96     // head dim padded to 3*32 for K=32 MFMA chunks
#define QKV_N 3840

typedef unsigned short u16;
typedef unsigned int u32;
typedef __bf16 bf16x8 __attribute__((ext_vector_type(8)));
typedef float f32x4 __attribute__((ext_vector_type(4)));

__device__ __forceinline__ u16 bf16_bits(float f) {
  __hip_bfloat16 b = __float2bfloat16(f);
  return *reinterpret_cast<u16*>(&b);
}
__device__ __forceinline__ float bf16_to_f(u16 u) {
  unsigned int x = ((unsigned int)u) << 16;
  return __uint_as_float(x);
}
__device__ __forceinline__ void gload_lds16(const u16* g, u16* l) {
  __builtin_amdgcn_global_load_lds(
      (const __attribute__((address_space(1))) void*)g,
      (__attribute__((address_space(3))) void*)l, 16, 0, 0);
}
__device__ __forceinline__ int imin(int a, int b) { return a < b ? a : b; }

// ---------------- fused fp32 -> bf16 convert: x | qkv_w | proj_w ----------------
#define XB_F4    983040
#define WQKV_F4  1228800
#define WPROJ_F4 409600
__global__ __launch_bounds__(256) void f32_to_bf16_3(const float* __restrict__ sx,
                                                     const float* __restrict__ sq,
                                                     const float* __restrict__ sp,
                                                     u16* __restrict__ dst) {
  int i = blockIdx.x * 256 + threadIdx.x;
  float4 v;
  if (i < XB_F4) v = reinterpret_cast<const float4*>(sx)[i];
  else if (i < XB_F4 + WQKV_F4) v = reinterpret_cast<const float4*>(sq)[i - XB_F4];
  else v = reinterpret_cast<const float4*>(sp)[i - XB_F4 - WQKV_F4];
  ushort4 o;
  o.x = bf16_bits(v.x); o.y = bf16_bits(v.y); o.z = bf16_bits(v.z); o.w = bf16_bits(v.w);
  reinterpret_cast<ushort4*>(dst)[i] = o;
}

// ---------------- NT GEMM: C[M][N] = A[M][K] * B[N][K]^T + bias ----------------
// 128x128 tile, BK=64, XOR-swizzled LDS (T2 both-sides via pre-swizzled source).
template<int OUT_F32>
__global__ __launch_bounds__(256) void gemm_nt(const u16* __restrict__ A,
                                               const u16* __restrict__ B,
                                               const float* __restrict__ bias,
                                               void* __restrict__ Cout,
                                               int M, int N, int K, int nbx) {
  __shared__ u16 As[128 * 64];
  __shared__ u16 Bs[128 * 64];
  const int t = threadIdx.x;
  const int lane = t & 63;
  const int wave = t >> 6;
  const int l15 = lane & 15, l4 = lane >> 4;
  const int wm = (wave >> 1) * 64, wn = (wave & 1) * 64;

  const int nwg = gridDim.x;
  const int lg = (blockIdx.x & 7) * (nwg >> 3) + (blockIdx.x >> 3);
  const int m0 = (lg / nbx) * 128, n0 = (lg % nbx) * 128;

  const u16* gA[4];
  const u16* gB[4];
  u16* lA[4];
  u16* lB[4];
  #pragma unroll
  for (int i = 0; i < 4; ++i) {
    const int c = i * 256 + t;
    const int row = c >> 3;
    const int col = ((c & 7) ^ (row & 7)) * 8;
    gA[i] = A + (size_t)(m0 + row) * K + col;
    gB[i] = B + (size_t)(n0 + row) * K + col;
    lA[i] = &As[c * 8];
    lB[i] = &Bs[c * 8];
  }

  int aoff[4][2], boff[4][2];
  #pragma unroll
  for (int i = 0; i < 4; ++i)
    #pragma unroll
    for (int kk = 0; kk < 2; ++kk) {
      aoff[i][kk] = (wm + i * 16 + l15) * 64 + ((kk * 4 + l4) ^ (l15 & 7)) * 8;
      boff[i][kk] = (wn + i * 16 + l15) * 64 + ((kk * 4 + l4) ^ (l15 & 7)) * 8;
    }

  f32x4 acc[4][4] = {};

  const int nk = K >> 6;
  for (int kt = 0; kt < nk; ++kt) {
    const int k0 = kt << 6;
    #pragma unroll
    for (int i = 0; i < 4; ++i) gload_lds16(gA[i] + k0, lA[i]);
    #pragma unroll
    for (int i = 0; i < 4; ++i) gload_lds16(gB[i] + k0, lB[i]);
    __syncthreads();
    bf16x8 af[4][2], bfr[4][2];
    #pragma unroll
    for (int i = 0; i < 4; ++i)
      #pragma unroll
      for (int kk = 0; kk < 2; ++kk) {
        af[i][kk]  = *reinterpret_cast<const bf16x8*>(&As[aoff[i][kk]]);
        bfr[i][kk] = *reinterpret_cast<const bf16x8*>(&Bs[boff[i][kk]]);
      }
    __builtin_amdgcn_s_setprio(1);
    #pragma unroll
    for (int kk = 0; kk < 2; ++kk)
      #pragma unroll
      for (int i = 0; i < 4; ++i)
        #pragma unroll
        for (int j = 0; j < 4; ++j)
          acc[i][j] = __builtin_amdgcn_mfma_f32_16x16x32_bf16(af[i][kk], bfr[j][kk],
                                                              acc[i][j], 0, 0, 0);
    __builtin_amdgcn_s_setprio(0);
    __syncthreads();
  }

  #pragma unroll
  for (int i = 0; i < 4; ++i) {
    #pragma unroll
    for (int j = 0; j < 4; ++j) {
      const int col = n0 + wn + j * 16 + l15;
      const float bv = bias[col];
      const int rowb = m0 + wm + i * 16 + l4 * 4;
      #pragma unroll
      for (int r = 0; r < 4; ++r) {
        float v = acc[i][j][r] + bv;
        if (OUT_F32)
          reinterpret_cast<float*>(Cout)[(size_t)(rowb + r) * N + col] = v;
        else
          reinterpret_cast<u16*>(Cout)[(size_t)(rowb + r) * N + col] = bf16_bits(v);
      }
    }
  }
}

// ---------------- fused RoPE-scatter + V-transpose (both read qkv) ----------------
// blocks [0, 12288): rope for (h = b/768, s-block = b%768 covering 4 rows)
// blocks [12288, 14208): v transpose, idx = (b-12288)*256+t
#define ROPE_NB 12288
#define VT_NB   1920
__global__ __launch_bounds__(256) void rope_vt(const u16* __restrict__ qkv,
                                               const float* __restrict__ cosb,
                                               const float* __restrict__ sinb,
                                               u16* __restrict__ qp,
                                               u16* __restrict__ kp,
                                               u16* __restrict__ vt) {
  const int b = blockIdx.x;
  const int t = threadIdx.x;
  if (b < ROPE_NB) {
    const int h = b / 768;
    const int sl = t >> 6;
    const int p = t & 63;
    const int s = (b % 768) * 4 + sl;
    const size_t ib = (size_t)s * QKV_N + h * HD;
    const size_t ob = ((size_t)h * S_LEN + s) * HDP;
    if (p < 40) {
      const float scale = 0.1118033988749895f;  // 1/sqrt(80)
      float q1 = bf16_to_f(qkv[ib + p]);
      float q2 = bf16_to_f(qkv[ib + 40 + p]);
      float k1 = bf16_to_f(qkv[ib + E_DIM + p]);
      float k2 = bf16_to_f(qkv[ib + E_DIM + 40 + p]);
      float c1 = cosb[(size_t)s * HD + p],      s1 = sinb[(size_t)s * HD + p];
      float c2 = cosb[(size_t)s * HD + 40 + p], s2 = sinb[(size_t)s * HD + 40 + p];
      qp[ob + p]      = bf16_bits((q1 * c1 - q2 * s1) * scale);
      qp[ob + 40 + p] = bf16_bits((q2 * c2 + q1 * s2) * scale);
      kp[ob + p]      = bf16_bits(k1 * c1 - k2 * s1);
      kp[ob + 40 + p] = bf16_bits(k2 * c2 + k1 * s2);
    } else if (p < 48) {
      const int pd = HD + (p - 40) * 2;
      qp[ob + pd] = 0; qp[ob + pd + 1] = 0;
      kp[ob + pd] = 0; kp[ob + pd + 1] = 0;
    }
  } else {
    const int idx = (b - ROPE_NB) * 256 + t;
    const int d = idx % HD;
    const int h = (idx / HD) % NH;
    const int sb = idx / (HD * NH);
    const int s0 = sb * 8;
    if (s0 >= S_LEN) return;
    u16 bb[8];
    #pragma unroll
    for (int j = 0; j < 8; ++j)
      bb[j] = qkv[(size_t)(s0 + j) * QKV_N + 2 * E_DIM + h * HD + d];
    uint4 pk;
    pk.x = bb[0] | ((unsigned)bb[1] << 16);
    pk.y = bb[2] | ((unsigned)bb[3] << 16);
    pk.z = bb[4] | ((unsigned)bb[5] << 16);
    pk.w = bb[6] | ((unsigned)bb[7] << 16);
    *reinterpret_cast<uint4*>(&vt[((size_t)h * HD + d) * S_LEN + s0]) = pk;
  }
}

// ---------------- segment-local flash attention, barrier-free, L2-direct K --------
// grid 768 = 16 heads x 48 q-blocks(64). 4 independent waves; wave owns 16 q rows.
// K+V per head ~1.1MB; XCD swizzle pins 2 heads per XCD L2 -> K frags read direct
// from L2 (no LDS staging, no __syncthreads in the loop).
// QK^T swapped: mfma(K,Q) -> S[k][q], q on lanes (l15), k in regs.
// PV swapped: mfma(V^T, P^T) -> O^T[d][q].
__global__ __launch_bounds__(256) void attn_fwd(const u16* __restrict__ qp,
                                                const u16* __restrict__ kp,
                                                const u16* __restrict__ vt,
                                                const int* __restrict__ cu, int ncu,
                                                u16* __restrict__ ao) {
  __shared__ u16 Pl[4][16][72];   // per-wave P^T staging, XOR-swizzled 16B chunks

  const int lg = ((blockIdx.x & 7) * 96) + (blockIdx.x >> 3);
  const int h = lg / 48;
  const int q0 = (lg % 48) * 64;

  const int t = threadIdx.x;
  const int wave = t >> 6;
  const int lane = t & 63;
  const int l15 = lane & 15, l4 = lane >> 4;
  const int qr = q0 + wave * 16;

  int lo = 0, hi = S_LEN;
  for (int i = 0; i + 1 < ncu; ++i) {
    int a = cu[i], b = cu[i + 1];
    if (q0 >= a && q0 < b) { lo = a; hi = b; }
  }
  const int nt = (hi - lo + 63) >> 6;

  const u16* qh = qp + (size_t)h * S_LEN * HDP;
  const u16* kh = kp + (size_t)h * S_LEN * HDP;
  const u16* vh = vt + (size_t)h * HD * S_LEN;

  // Q fragments (B-operand: col=l15 is q, k=l4*8+j)
  bf16x8 qf[3];
  #pragma unroll
  for (int c = 0; c < 3; ++c)
    qf[c] = *reinterpret_cast<const bf16x8*>(&qh[(size_t)(qr + l15) * HDP + c * 32 + l4 * 8]);

  f32x4 oacc[5] = {};           // O^T: d = df*16 + l4*4 + r, q = l15
  float mrow = -INFINITY, lrow = 0.f;
  const float L2E = 1.4426950408889634f;

  // kt-invariant swizzled P LDS offsets
  int pwr[4];
  #pragma unroll
  for (int f = 0; f < 4; ++f)
    pwr[f] = ((f * 2 + (l4 >> 1)) ^ (l15 & 7)) * 8 + (l4 & 1) * 4;
  int prd[2];
  #pragma unroll
  for (int kc = 0; kc < 2; ++kc)
    prd[kc] = ((kc * 4 + l4) ^ (l15 & 7)) * 8;

  for (int ti = 0; ti < nt; ++ti) {
    const int kb = lo + ti * 64;

    // V loads early (A-operand of PV: rows d=df*16+l15, k contiguous)
    bf16x8 vreg[2][5];
    #pragma unroll
    for (int kc = 0; kc < 2; ++kc)
      #pragma unroll
      for (int df = 0; df < 5; ++df)
        vreg[kc][df] = *reinterpret_cast<const bf16x8*>(
            &vh[(size_t)(df * 16 + l15) * S_LEN + kb + kc * 32 + l4 * 8]);

    // QK^T swapped, K fragments direct from L2: sc[f] = S[k = f*16+l4*4+r][q = l15]
    f32x4 sc[4];
    #pragma unroll
    for (int f = 0; f < 4; ++f) { f32x4 z = {0.f, 0.f, 0.f, 0.f}; sc[f] = z; }
    __builtin_amdgcn_s_setprio(1);
    #pragma unroll
    for (int f = 0; f < 4; ++f)
      #pragma unroll
      for (int c = 0; c < 3; ++c) {
        bf16x8 kf = *reinterpret_cast<const bf16x8*>(
            &kh[(size_t)(kb + f * 16 + l15) * HDP + c * 32 + l4 * 8]);
        sc[f] = __builtin_amdgcn_mfma_f32_16x16x32_bf16(kf, qf[c], sc[f], 0, 0, 0);
      }
    __builtin_amdgcn_s_setprio(0);

    // mask (never taken for 64-multiple segments; kept for safety)
    if (kb + 64 > hi) {
      #pragma unroll
      for (int f = 0; f < 4; ++f)
        #pragma unroll
        for (int r = 0; r < 4; ++r)
          if (kb + f * 16 + l4 * 4 + r >= hi) sc[f][r] = -INFINITY;
    }

    // per-lane (per-q) max: 16 in-reg + 2 shuffles across l4
    float tm = -INFINITY;
    #pragma unroll
    for (int f = 0; f < 4; ++f)
      #pragma unroll
      for (int r = 0; r < 4; ++r) tm = fmaxf(tm, sc[f][r]);
    tm = fmaxf(tm, __shfl_xor(tm, 16, 64));
    tm = fmaxf(tm, __shfl_xor(tm, 32, 64));

    // defer-max (T13): rescale only when max grew by > 8
    if (__any(tm > mrow + 8.f)) {
      float mn = fmaxf(mrow, tm);
      float corr = exp2f((mrow - mn) * L2E);
      mrow = mn;
      lrow *= corr;
      #pragma unroll
      for (int df = 0; df < 5; ++df)
        #pragma unroll
        for (int r = 0; r < 4; ++r) oacc[df][r] *= corr;
    }

    // P = exp2((S-m)*log2e); in-lane partial sum; pack; 4x ds_write_b64
    float rs = 0.f;
    #pragma unroll
    for (int f = 0; f < 4; ++f) {
      float p0 = exp2f((sc[f][0] - mrow) * L2E);
      float p1 = exp2f((sc[f][1] - mrow) * L2E);
      float p2 = exp2f((sc[f][2] - mrow) * L2E);
      float p3 = exp2f((sc[f][3] - mrow) * L2E);
      rs += (p0 + p1) + (p2 + p3);
      uint2 w;
      w.x = (u32)bf16_bits(p0) | ((u32)bf16_bits(p1) << 16);
      w.y = (u32)bf16_bits(p2) | ((u32)bf16_bits(p3) << 16);
      *reinterpret_cast<uint2*>(&Pl[wave][l15][pwr[f]]) = w;
    }
    rs += __shfl_xor(rs, 16, 64);
    rs += __shfl_xor(rs, 32, 64);
    lrow += rs;

    asm volatile("s_waitcnt lgkmcnt(0)" ::: "memory");  // own-wave P writes visible

    // PV swapped: oacc[df] += mfma(A=V^T frag, B=P^T frag)
    __builtin_amdgcn_s_setprio(1);
    #pragma unroll
    for (int kc = 0; kc < 2; ++kc) {
      bf16x8 pf = *reinterpret_cast<const bf16x8*>(&Pl[wave][l15][prd[kc]]);
      #pragma unroll
      for (int df = 0; df < 5; ++df)
        oacc[df] = __builtin_amdgcn_mfma_f32_16x16x32_bf16(vreg[kc][df], pf, oacc[df], 0, 0, 0);
    }
    __builtin_amdgcn_s_setprio(0);
  }

  // epilogue: O^T[d][q] -> ao[q][h*HD+d]; lrow is per-lane (q = l15)
  const float inv = 1.0f / lrow;
  #pragma unroll
  for (int df = 0; df < 5; ++df) {
    ushort4 o;
    o.x = bf16_bits(oacc[df][0] * inv);
    o.y = bf16_bits(oacc[df][1] * inv);
    o.z = bf16_bits(oacc[df][2] * inv);
    o.w = bf16_bits(oacc[df][3] * inv);
    *reinterpret_cast<ushort4*>(
        &ao[(size_t)(qr + l15) * E_DIM + h * HD + df * 16 + l4 * 4]) = o;
  }
}

// ---------------- host launch ----------------
extern "C" void kernel_launch(void* const* d_in, const int* in_sizes, int n_in,
                              void* d_out, int out_size, void* d_ws, size_t ws_size,
                              hipStream_t stream) {
  const float* x      = (const float*)d_in[0];
  const int*   cu     = (const int*)d_in[1];
  const float* cosb   = (const float*)d_in[2];
  const float* sinb   = (const float*)d_in[3];
  const float* qkv_w  = (const float*)d_in[4];
  const float* qkv_b  = (const float*)d_in[5];
  const float* proj_w = (const float*)d_in[6];
  const float* proj_b = (const float*)d_in[7];
  float* out = (float*)d_out;

  u16* xb     = (u16*)d_ws;
  u16* wqkvb  = xb     + (size_t)S_LEN * E_DIM;
  u16* wprojb = wqkvb  + (size_t)3 * E_DIM * E_DIM;
  u16* qkv    = wprojb + (size_t)E_DIM * E_DIM;
  u16* qp     = qkv    + (size_t)S_LEN * QKV_N;
  u16* kp     = qp     + (size_t)NH * S_LEN * HDP;
  u16* vt     = kp     + (size_t)NH * S_LEN * HDP;
  u16* attn   = vt     + (size_t)NH * HD * S_LEN;

  const int nf4 = XB_F4 + WQKV_F4 + WPROJ_F4;
  f32_to_bf16_3<<<nf4 / 256, 256, 0, stream>>>(x, qkv_w, proj_w, xb);

  gemm_nt<0><<<(QKV_N / 128) * (S_LEN / 128), 256, 0, stream>>>(
      xb, wqkvb, qkv_b, qkv, S_LEN, QKV_N, E_DIM, QKV_N / 128);

  rope_vt<<<ROPE_NB + VT_NB, 256, 0, stream>>>(qkv, cosb, sinb, qp, kp, vt);

  attn_fwd<<<NH * (S_LEN / 64), 256, 0, stream>>>(qp, kp, vt, cu, in_sizes[1], attn);

  gemm_nt<1><<<(E_DIM / 128) * (S_LEN / 128), 256, 0, stream>>>(
      attn, wprojb, proj_b, out, S_LEN, E_DIM, E_DIM, E_DIM / 128);
}

// Round 6
// 109.689 us; speedup vs baseline: 1.1754x; 1.1754x over previous
//
#include <hip/hip_runtime.h>
#include <hip/hip_bf16.h>

#define S_LEN 3072
#define E_DIM 1280
#define NH 16
#define HD 80      // head dim
#define HDP 96     // head dim padded to 3*32 for K=32 MFMA chunks
#define QKV_N 3840

typedef unsigned short u16;
typedef unsigned int u32;
typedef __bf16 bf16x8 __attribute__((ext_vector_type(8)));
typedef float f32x4 __attribute__((ext_vector_type(4)));

__device__ __forceinline__ u16 bf16_bits(float f) {
  __hip_bfloat16 b = __float2bfloat16(f);
  return *reinterpret_cast<u16*>(&b);
}
__device__ __forceinline__ float bf16_to_f(u16 u) {
  unsigned int x = ((unsigned int)u) << 16;
  return __uint_as_float(x);
}
__device__ __forceinline__ void gload_lds16(const u16* g, u16* l) {
  __builtin_amdgcn_global_load_lds(
      (const __attribute__((address_space(1))) void*)g,
      (__attribute__((address_space(3))) void*)l, 16, 0, 0);
}
__device__ __forceinline__ int imin(int a, int b) { return a < b ? a : b; }

// ---------------- fused fp32 -> bf16 convert: x | qkv_w | proj_w ----------------
#define XB_F4    983040
#define WQKV_F4  1228800
#define WPROJ_F4 409600
__global__ __launch_bounds__(256) void f32_to_bf16_3(const float* __restrict__ sx,
                                                     const float* __restrict__ sq,
                                                     const float* __restrict__ sp,
                                                     u16* __restrict__ dst) {
  int i = blockIdx.x * 256 + threadIdx.x;
  float4 v;
  if (i < XB_F4) v = reinterpret_cast<const float4*>(sx)[i];
  else if (i < XB_F4 + WQKV_F4) v = reinterpret_cast<const float4*>(sq)[i - XB_F4];
  else v = reinterpret_cast<const float4*>(sp)[i - XB_F4 - WQKV_F4];
  ushort4 o;
  o.x = bf16_bits(v.x); o.y = bf16_bits(v.y); o.z = bf16_bits(v.z); o.w = bf16_bits(v.w);
  reinterpret_cast<ushort4*>(dst)[i] = o;
}

// ---------------- NT GEMM: C[M][N] = A[M][K] * B[N][K]^T + bias ----------------
// 128x128 tile, BK=64, XOR-swizzled LDS (T2 both-sides via pre-swizzled source).
template<int OUT_F32>
__global__ __launch_bounds__(256) void gemm_nt(const u16* __restrict__ A,
                                               const u16* __restrict__ B,
                                               const float* __restrict__ bias,
                                               void* __restrict__ Cout,
                                               int M, int N, int K, int nbx) {
  __shared__ u16 As[128 * 64];
  __shared__ u16 Bs[128 * 64];
  const int t = threadIdx.x;
  const int lane = t & 63;
  const int wave = t >> 6;
  const int l15 = lane & 15, l4 = lane >> 4;
  const int wm = (wave >> 1) * 64, wn = (wave & 1) * 64;

  const int nwg = gridDim.x;
  const int lg = (blockIdx.x & 7) * (nwg >> 3) + (blockIdx.x >> 3);
  const int m0 = (lg / nbx) * 128, n0 = (lg % nbx) * 128;

  const u16* gA[4];
  const u16* gB[4];
  u16* lA[4];
  u16* lB[4];
  #pragma unroll
  for (int i = 0; i < 4; ++i) {
    const int c = i * 256 + t;
    const int row = c >> 3;
    const int col = ((c & 7) ^ (row & 7)) * 8;
    gA[i] = A + (size_t)(m0 + row) * K + col;
    gB[i] = B + (size_t)(n0 + row) * K + col;
    lA[i] = &As[c * 8];
    lB[i] = &Bs[c * 8];
  }

  int aoff[4][2], boff[4][2];
  #pragma unroll
  for (int i = 0; i < 4; ++i)
    #pragma unroll
    for (int kk = 0; kk < 2; ++kk) {
      aoff[i][kk] = (wm + i * 16 + l15) * 64 + ((kk * 4 + l4) ^ (l15 & 7)) * 8;
      boff[i][kk] = (wn + i * 16 + l15) * 64 + ((kk * 4 + l4) ^ (l15 & 7)) * 8;
    }

  f32x4 acc[4][4] = {};

  const int nk = K >> 6;
  for (int kt = 0; kt < nk; ++kt) {
    const int k0 = kt << 6;
    #pragma unroll
    for (int i = 0; i < 4; ++i) gload_lds16(gA[i] + k0, lA[i]);
    #pragma unroll
    for (int i = 0; i < 4; ++i) gload_lds16(gB[i] + k0, lB[i]);
    __syncthreads();
    bf16x8 af[4][2], bfr[4][2];
    #pragma unroll
    for (int i = 0; i < 4; ++i)
      #pragma unroll
      for (int kk = 0; kk < 2; ++kk) {
        af[i][kk]  = *reinterpret_cast<const bf16x8*>(&As[aoff[i][kk]]);
        bfr[i][kk] = *reinterpret_cast<const bf16x8*>(&Bs[boff[i][kk]]);
      }
    __builtin_amdgcn_s_setprio(1);
    #pragma unroll
    for (int kk = 0; kk < 2; ++kk)
      #pragma unroll
      for (int i = 0; i < 4; ++i)
        #pragma unroll
        for (int j = 0; j < 4; ++j)
          acc[i][j] = __builtin_amdgcn_mfma_f32_16x16x32_bf16(af[i][kk], bfr[j][kk],
                                                              acc[i][j], 0, 0, 0);
    __builtin_amdgcn_s_setprio(0);
    __syncthreads();
  }

  #pragma unroll
  for (int i = 0; i < 4; ++i) {
    #pragma unroll
    for (int j = 0; j < 4; ++j) {
      const int col = n0 + wn + j * 16 + l15;
      const float bv = bias[col];
      const int rowb = m0 + wm + i * 16 + l4 * 4;
      #pragma unroll
      for (int r = 0; r < 4; ++r) {
        float v = acc[i][j][r] + bv;
        if (OUT_F32)
          reinterpret_cast<float*>(Cout)[(size_t)(rowb + r) * N + col] = v;
        else
          reinterpret_cast<u16*>(Cout)[(size_t)(rowb + r) * N + col] = bf16_bits(v);
      }
    }
  }
}

// ---------------- fused RoPE-scatter + V-transpose (both read qkv) ----------------
#define ROPE_NB 12288
#define VT_NB   1920
__global__ __launch_bounds__(256) void rope_vt(const u16* __restrict__ qkv,
                                               const float* __restrict__ cosb,
                                               const float* __restrict__ sinb,
                                               u16* __restrict__ qp,
                                               u16* __restrict__ kp,
                                               u16* __restrict__ vt) {
  const int b = blockIdx.x;
  const int t = threadIdx.x;
  if (b < ROPE_NB) {
    const int h = b / 768;
    const int sl = t >> 6;
    const int p = t & 63;
    const int s = (b % 768) * 4 + sl;
    const size_t ib = (size_t)s * QKV_N + h * HD;
    const size_t ob = ((size_t)h * S_LEN + s) * HDP;
    if (p < 40) {
      const float scale = 0.1118033988749895f;  // 1/sqrt(80)
      float q1 = bf16_to_f(qkv[ib + p]);
      float q2 = bf16_to_f(qkv[ib + 40 + p]);
      float k1 = bf16_to_f(qkv[ib + E_DIM + p]);
      float k2 = bf16_to_f(qkv[ib + E_DIM + 40 + p]);
      float c1 = cosb[(size_t)s * HD + p],      s1 = sinb[(size_t)s * HD + p];
      float c2 = cosb[(size_t)s * HD + 40 + p], s2 = sinb[(size_t)s * HD + 40 + p];
      qp[ob + p]      = bf16_bits((q1 * c1 - q2 * s1) * scale);
      qp[ob + 40 + p] = bf16_bits((q2 * c2 + q1 * s2) * scale);
      kp[ob + p]      = bf16_bits(k1 * c1 - k2 * s1);
      kp[ob + 40 + p] = bf16_bits(k2 * c2 + k1 * s2);
    } else if (p < 48) {
      const int pd = HD + (p - 40) * 2;
      qp[ob + pd] = 0; qp[ob + pd + 1] = 0;
      kp[ob + pd] = 0; kp[ob + pd + 1] = 0;
    }
  } else {
    const int idx = (b - ROPE_NB) * 256 + t;
    const int d = idx % HD;
    const int h = (idx / HD) % NH;
    const int sb = idx / (HD * NH);
    const int s0 = sb * 8;
    if (s0 >= S_LEN) return;
    u16 bb[8];
    #pragma unroll
    for (int j = 0; j < 8; ++j)
      bb[j] = qkv[(size_t)(s0 + j) * QKV_N + 2 * E_DIM + h * HD + d];
    uint4 pk;
    pk.x = bb[0] | ((unsigned)bb[1] << 16);
    pk.y = bb[2] | ((unsigned)bb[3] << 16);
    pk.z = bb[4] | ((unsigned)bb[5] << 16);
    pk.w = bb[6] | ((unsigned)bb[7] << 16);
    *reinterpret_cast<uint4*>(&vt[((size_t)h * HD + d) * S_LEN + s0]) = pk;
  }
}

// ---------------- segment-local flash attention ----------------
// K AND V staged in LDS (coalesced global loads, XOR-swizzled conflict-free
// b128 frag reads); next-tile register prefetch; 2 barriers/tile.
// QK^T swapped: mfma(K,Q) -> S[k][q], q on lanes (l15), k in regs.
// PV swapped: mfma(V^T, P^T) -> O^T[d][q].
__global__ __launch_bounds__(256, 3) void attn_fwd(const u16* __restrict__ qp,
                                                   const u16* __restrict__ kp,
                                                   const u16* __restrict__ vt,
                                                   const int* __restrict__ cu, int ncu,
                                                   u16* __restrict__ ao) {
  __shared__ u16 Ks[64 * 128];    // row r: logical 16B chunk c at phys c^(r&7)
  __shared__ u16 Vs[80 * 64];     // row d: logical chunk c (of 8) at phys c^(d&7)
  __shared__ u16 Pl[4][16][72];   // per-wave P^T staging, XOR-swizzled 16B chunks

  const int lg = ((blockIdx.x & 7) * 96) + (blockIdx.x >> 3);
  const int h = lg / 48;
  const int q0 = (lg % 48) * 64;

  const int t = threadIdx.x;
  const int wave = t >> 6;
  const int lane = t & 63;
  const int l15 = lane & 15, l4 = lane >> 4;
  const int qr = q0 + wave * 16;

  int lo = 0, hi = S_LEN;
  for (int i = 0; i + 1 < ncu; ++i) {
    int a = cu[i], b = cu[i + 1];
    if (q0 >= a && q0 < b) { lo = a; hi = b; }
  }
  const int nt = (hi - lo + 63) >> 6;

  const u16* qh = qp + (size_t)h * S_LEN * HDP;
  const u16* kh = kp + (size_t)h * S_LEN * HDP;
  const u16* vh = vt + (size_t)h * HD * S_LEN;

  // Q fragments (B-operand: col=l15 is q, k=l4*8+j)
  bf16x8 qf[3];
  #pragma unroll
  for (int c = 0; c < 3; ++c)
    qf[c] = *reinterpret_cast<const bf16x8*>(&qh[(size_t)(qr + l15) * HDP + c * 32 + l4 * 8]);

  // staging maps: K 768 chunks (64 rows x 12), V 640 chunks (80 rows x 8)
  int kr[3], kcc[3], kw[3];
  #pragma unroll
  for (int i = 0; i < 3; ++i) {
    const int c2 = i * 256 + t;
    kr[i] = c2 / 12; kcc[i] = c2 % 12;
    kw[i] = kr[i] * 128 + ((kcc[i] ^ (kr[i] & 7)) * 8);
  }
  int vd[3], vcc[3], vwo[3];
  #pragma unroll
  for (int i = 0; i < 3; ++i) {
    const int c2 = i * 256 + t;
    vd[i] = c2 >> 3; vcc[i] = c2 & 7;
    vwo[i] = vd[i] * 64 + ((vcc[i] ^ (vd[i] & 7)) * 8);
  }
  const bool v2 = (t < 128);  // third V chunk only for waves 0,1

  // prologue: stage tile 0
  {
    const int kbv = imin(lo, S_LEN - 64);
    bf16x8 kstg[3], vstg[3];
    #pragma unroll
    for (int i = 0; i < 3; ++i)
      kstg[i] = *reinterpret_cast<const bf16x8*>(
          &kh[(size_t)imin(lo + kr[i], S_LEN - 1) * HDP + kcc[i] * 8]);
    #pragma unroll
    for (int i = 0; i < 2; ++i)
      vstg[i] = *reinterpret_cast<const bf16x8*>(&vh[(size_t)vd[i] * S_LEN + kbv + vcc[i] * 8]);
    if (v2)
      vstg[2] = *reinterpret_cast<const bf16x8*>(&vh[(size_t)vd[2] * S_LEN + kbv + vcc[2] * 8]);
    #pragma unroll
    for (int i = 0; i < 3; ++i) *reinterpret_cast<bf16x8*>(&Ks[kw[i]]) = kstg[i];
    #pragma unroll
    for (int i = 0; i < 2; ++i) *reinterpret_cast<bf16x8*>(&Vs[vwo[i]]) = vstg[i];
    if (v2) *reinterpret_cast<bf16x8*>(&Vs[vwo[2]]) = vstg[2];
    __syncthreads();
  }

  f32x4 oacc[5] = {};           // O^T: d = df*16 + l4*4 + r, q = l15
  float mrow = -INFINITY, lrow = 0.f;
  const float L2E = 1.4426950408889634f;

  // kt-invariant swizzled P LDS offsets
  int pwr[4];
  #pragma unroll
  for (int f = 0; f < 4; ++f)
    pwr[f] = ((f * 2 + (l4 >> 1)) ^ (l15 & 7)) * 8 + (l4 & 1) * 4;
  int prd[2];
  #pragma unroll
  for (int kc = 0; kc < 2; ++kc)
    prd[kc] = ((kc * 4 + l4) ^ (l15 & 7)) * 8;

  for (int ti = 0; ti < nt; ++ti) {
    const int kb = lo + ti * 64;
    const bool more = (ti + 1) < nt;

    // issue next-tile staging loads early (held in regs; ds_write after barrier)
    bf16x8 kstg[3], vstg[3];
    if (more) {
      const int kb2 = kb + 64;
      const int kbv = imin(kb2, S_LEN - 64);
      #pragma unroll
      for (int i = 0; i < 3; ++i)
        kstg[i] = *reinterpret_cast<const bf16x8*>(
            &kh[(size_t)imin(kb2 + kr[i], S_LEN - 1) * HDP + kcc[i] * 8]);
      #pragma unroll
      for (int i = 0; i < 2; ++i)
        vstg[i] = *reinterpret_cast<const bf16x8*>(&vh[(size_t)vd[i] * S_LEN + kbv + vcc[i] * 8]);
      if (v2)
        vstg[2] = *reinterpret_cast<const bf16x8*>(&vh[(size_t)vd[2] * S_LEN + kbv + vcc[2] * 8]);
    }

    // QK^T swapped from LDS: sc[f] = S[k = f*16+l4*4+r][q = l15]
    f32x4 sc[4];
    #pragma unroll
    for (int f = 0; f < 4; ++f) { f32x4 z = {0.f, 0.f, 0.f, 0.f}; sc[f] = z; }
    __builtin_amdgcn_s_setprio(1);
    #pragma unroll
    for (int f = 0; f < 4; ++f)
      #pragma unroll
      for (int c = 0; c < 3; ++c) {
        bf16x8 kf = *reinterpret_cast<const bf16x8*>(
            &Ks[(f * 16 + l15) * 128 + (((c * 4 + l4) ^ (l15 & 7)) * 8)]);
        sc[f] = __builtin_amdgcn_mfma_f32_16x16x32_bf16(kf, qf[c], sc[f], 0, 0, 0);
      }
    __builtin_amdgcn_s_setprio(0);

    // mask (never taken for 64-multiple segments; kept for safety)
    if (kb + 64 > hi) {
      #pragma unroll
      for (int f = 0; f < 4; ++f)
        #pragma unroll
        for (int r = 0; r < 4; ++r)
          if (kb + f * 16 + l4 * 4 + r >= hi) sc[f][r] = -INFINITY;
    }

    // per-lane (per-q) max: 16 in-reg + 2 shuffles across l4
    float tm = -INFINITY;
    #pragma unroll
    for (int f = 0; f < 4; ++f)
      #pragma unroll
      for (int r = 0; r < 4; ++r) tm = fmaxf(tm, sc[f][r]);
    tm = fmaxf(tm, __shfl_xor(tm, 16, 64));
    tm = fmaxf(tm, __shfl_xor(tm, 32, 64));

    // defer-max (T13): rescale only when max grew by > 8
    if (__any(tm > mrow + 8.f)) {
      float mn = fmaxf(mrow, tm);
      float corr = exp2f((mrow - mn) * L2E);
      mrow = mn;
      lrow *= corr;
      #pragma unroll
      for (int df = 0; df < 5; ++df)
        #pragma unroll
        for (int r = 0; r < 4; ++r) oacc[df][r] *= corr;
    }

    // P = exp2((S-m)*log2e); in-lane partial sum; pack; 4x ds_write_b64
    float rs = 0.f;
    #pragma unroll
    for (int f = 0; f < 4; ++f) {
      float p0 = exp2f((sc[f][0] - mrow) * L2E);
      float p1 = exp2f((sc[f][1] - mrow) * L2E);
      float p2 = exp2f((sc[f][2] - mrow) * L2E);
      float p3 = exp2f((sc[f][3] - mrow) * L2E);
      rs += (p0 + p1) + (p2 + p3);
      uint2 w;
      w.x = (u32)bf16_bits(p0) | ((u32)bf16_bits(p1) << 16);
      w.y = (u32)bf16_bits(p2) | ((u32)bf16_bits(p3) << 16);
      *reinterpret_cast<uint2*>(&Pl[wave][l15][pwr[f]]) = w;
    }
    rs += __shfl_xor(rs, 16, 64);
    rs += __shfl_xor(rs, 32, 64);
    lrow += rs;

    asm volatile("s_waitcnt lgkmcnt(0)" ::: "memory");  // own-wave P writes visible

    // PV swapped: oacc[df] += mfma(A=V^T frag from LDS, B=P^T frag)
    __builtin_amdgcn_s_setprio(1);
    #pragma unroll
    for (int kc = 0; kc < 2; ++kc) {
      bf16x8 pf = *reinterpret_cast<const bf16x8*>(&Pl[wave][l15][prd[kc]]);
      #pragma unroll
      for (int df = 0; df < 5; ++df) {
        bf16x8 vf = *reinterpret_cast<const bf16x8*>(
            &Vs[(df * 16 + l15) * 64 + (((kc * 4 + l4) ^ (l15 & 7)) * 8)]);
        oacc[df] = __builtin_amdgcn_mfma_f32_16x16x32_bf16(vf, pf, oacc[df], 0, 0, 0);
      }
    }
    __builtin_amdgcn_s_setprio(0);

    if (more) {
      __syncthreads();   // all waves done reading Ks/Vs
      #pragma unroll
      for (int i = 0; i < 3; ++i) *reinterpret_cast<bf16x8*>(&Ks[kw[i]]) = kstg[i];
      #pragma unroll
      for (int i = 0; i < 2; ++i) *reinterpret_cast<bf16x8*>(&Vs[vwo[i]]) = vstg[i];
      if (v2) *reinterpret_cast<bf16x8*>(&Vs[vwo[2]]) = vstg[2];
      __syncthreads();   // staged tile visible
    }
  }

  // epilogue: O^T[d][q] -> ao[q][h*HD+d]; lrow is per-lane (q = l15)
  const float inv = 1.0f / lrow;
  #pragma unroll
  for (int df = 0; df < 5; ++df) {
    ushort4 o;
    o.x = bf16_bits(oacc[df][0] * inv);
    o.y = bf16_bits(oacc[df][1] * inv);
    o.z = bf16_bits(oacc[df][2] * inv);
    o.w = bf16_bits(oacc[df][3] * inv);
    *reinterpret_cast<ushort4*>(
        &ao[(size_t)(qr + l15) * E_DIM + h * HD + df * 16 + l4 * 4]) = o;
  }
}

// ---------------- host launch ----------------
extern "C" void kernel_launch(void* const* d_in, const int* in_sizes, int n_in,
                              void* d_out, int out_size, void* d_ws, size_t ws_size,
                              hipStream_t stream) {
  const float* x      = (const float*)d_in[0];
  const int*   cu     = (const int*)d_in[1];
  const float* cosb   = (const float*)d_in[2];
  const float* sinb   = (const float*)d_in[3];
  const float* qkv_w  = (const float*)d_in[4];
  const float* qkv_b  = (const float*)d_in[5];
  const float* proj_w = (const float*)d_in[6];
  const float* proj_b = (const float*)d_in[7];
  float* out = (float*)d_out;

  u16* xb     = (u16*)d_ws;
  u16* wqkvb  = xb     + (size_t)S_LEN * E_DIM;
  u16* wprojb = wqkvb  + (size_t)3 * E_DIM * E_DIM;
  u16* qkv    = wprojb + (size_t)E_DIM * E_DIM;
  u16* qp     = qkv    + (size_t)S_LEN * QKV_N;
  u16* kp     = qp     + (size_t)NH * S_LEN * HDP;
  u16* vt     = kp     + (size_t)NH * S_LEN * HDP;
  u16* attn   = vt     + (size_t)NH * HD * S_LEN;

  const int nf4 = XB_F4 + WQKV_F4 + WPROJ_F4;
  f32_to_bf16_3<<<nf4 / 256, 256, 0, stream>>>(x, qkv_w, proj_w, xb);

  gemm_nt<0><<<(QKV_N / 128) * (S_LEN / 128), 256, 0, stream>>>(
      xb, wqkvb, qkv_b, qkv, S_LEN, QKV_N, E_DIM, QKV_N / 128);

  rope_vt<<<ROPE_NB + VT_NB, 256, 0, stream>>>(qkv, cosb, sinb, qp, kp, vt);

  attn_fwd<<<NH * (S_LEN / 64), 256, 0, stream>>>(qp, kp, vt, cu, in_sizes[1], attn);

  gemm_nt<1><<<(E_DIM / 128) * (S_LEN / 128), 256, 0, stream>>>(
      attn, wprojb, proj_b, out, S_LEN, E_DIM, E_DIM, E_DIM / 128);
}